// Round 3
// baseline (128.851 us; speedup 1.0000x reference)
//
#include <hip/hip_runtime.h>

typedef __attribute__((ext_vector_type(4))) int int4v;

#define AS1 __attribute__((address_space(1)))
#define AS3 __attribute__((address_space(3)))

#define BAR()   __builtin_amdgcn_s_barrier()
#define LGKM0() asm volatile("s_waitcnt lgkmcnt(0)" ::: "memory")

// stage one 64-row x 128B unit: LDS dest linear, global source inverse-swizzled
// (rule #21: source permutation == read permutation, col ^= (row&7)<<4)
#define STG_A(sb, rowbase, k0) \
    __builtin_amdgcn_global_load_lds( \
        (const AS1 void*)(aSrcBase + (size_t)(rowbase) * K + (k0)), \
        (AS3 void*)(ldsDestA + (sb) + (rowbase) * 128), 16, 0, 0)
#define STG_B(sb, rowbase, k0) \
    __builtin_amdgcn_global_load_lds( \
        (const AS1 void*)(bSrcBase + (size_t)(rowbase) * K + (k0)), \
        (AS3 void*)(ldsDestB + (sb) + (rowbase) * 128), 16, 0, 0)

#define LDA(mq, sb) \
    { _Pragma("unroll") for (int m = 0; m < 4; ++m) { \
        const int rb = (sb) + ((aRow0 + ((mq) << 6) + (m << 4)) << 7); \
        a[m][0] = *(const int4v*)(ls + rb + colx0); \
        a[m][1] = *(const int4v*)(ls + rb + colx1); } }

#define LDB(nq, sb) \
    { _Pragma("unroll") for (int n = 0; n < 2; ++n) { \
        const int rb = (sb) + 32768 + ((bRow0 + ((nq) << 5) + (n << 4)) << 7); \
        b[(nq)*2 + n][0] = *(const int4v*)(ls + rb + colx0); \
        b[(nq)*2 + n][1] = *(const int4v*)(ls + rb + colx1); } }

#define MMA(mq, nq) \
    { __builtin_amdgcn_s_setprio(1); \
      _Pragma("unroll") for (int m = 0; m < 4; ++m) \
      _Pragma("unroll") for (int n = 0; n < 2; ++n) { \
        acc[(mq)*4 + m][(nq)*2 + n] = __builtin_amdgcn_mfma_i32_16x16x64_i8( \
            a[m][0], b[(nq)*2 + n][0], acc[(mq)*4 + m][(nq)*2 + n], 0, 0, 0); \
        acc[(mq)*4 + m][(nq)*2 + n] = __builtin_amdgcn_mfma_i32_16x16x64_i8( \
            a[m][1], b[(nq)*2 + n][1], acc[(mq)*4 + m][(nq)*2 + n], 0, 0, 0); } \
      __builtin_amdgcn_s_setprio(0); }

// ---------------------------------------------------------------------------
// Pack both int32->int8 operands in one launch (memory-bound).
__global__ __launch_bounds__(256) void pack_both_kernel(
    const int* __restrict__ x, const int* __restrict__ w,
    int* __restrict__ x8, int* __restrict__ w8, int n4x, int n4w)
{
    int i = blockIdx.x * blockDim.x + threadIdx.x;
    const int stride = gridDim.x * blockDim.x;
    const int tot = n4x + n4w;
    for (; i < tot; i += stride) {
        const bool isx = i < n4x;
        const int4v v = isx ? ((const int4v*)x)[i] : ((const int4v*)w)[i - n4x];
        const int p = (v.x & 255) | ((v.y & 255) << 8) | ((v.z & 255) << 16) | ((v.w & 255) << 24);
        if (isx) x8[i] = p; else w8[i - n4x] = p;
    }
}

// ---------------------------------------------------------------------------
// Persistent 256x256-tile GEMM: grid=256 (1 block/CU), each block sweeps
// multiple tiles so tile t's store eviction overlaps tile t+1's K-loop.
// 8 waves (2Mx4N), BK=128 i8, 8-phase counted-vmcnt schedule, 128 KiB LDS.
__global__ __launch_bounds__(512, 2) void gemm_i8_256p(
    const char* __restrict__ A8, const char* __restrict__ B8,
    const float* __restrict__ scale, const int* __restrict__ bias,
    float* __restrict__ out, int M, int N, int K,
    int mTiles, int nTiles, int chunked)
{
    extern __shared__ __attribute__((aligned(16))) char ls[];

    const int tid  = threadIdx.x;
    const int lane = tid & 63;
    const int wid  = tid >> 6;
    const int wr   = wid >> 2;      // 0..1 (M)
    const int wc   = wid & 3;       // 0..3 (N)
    const int l15  = lane & 15;
    const int hi16 = lane >> 4;

    // per-thread swizzled read columns for kk=0,1 (T2)
    const int sw    = (l15 & 7) << 4;
    const int colx0 = ((hi16 << 4)) ^ sw;
    const int colx1 = (64 + (hi16 << 4)) ^ sw;
    const int aRow0 = (wr << 7) + l15;
    const int bRow0 = (wc << 6) + l15;

    // staging geometry (thread t: row t>>3, 16B slot t&7; dest == base+tid*16)
    const int srow  = tid >> 3;
    const int sslot = tid & 7;
    const int scol  = ((sslot ^ (srow & 7)) << 4);
    char* ldsDestA = ls + srow * 128 + (sslot << 4);
    char* ldsDestB = ls + 32768 + srow * 128 + (sslot << 4);

    const int nkt = K >> 7;         // K/128 (even; host guarantees K%256==0)
    const int nit = nkt >> 1;
    const int nwg = mTiles * nTiles;

    int4v acc[8][4];
    int4v a[4][2], b[4][2];

    for (int idx = blockIdx.x; idx < nwg; idx += gridDim.x) {
        // tile map: XCD-chunked (block stays on one XCD; B-panel constant/block)
        int mt, nt;
        if (chunked) {
            const int x = idx & 7, c = idx >> 3;
            mt = x * (mTiles >> 3) + c / nTiles;
            nt = c % nTiles;
        } else {
            mt = idx / nTiles;
            nt = idx % nTiles;
        }
        const int m0 = mt << 8, n0 = nt << 8;
        const char* aSrcBase = A8 + (size_t)(m0 + srow) * K + scol;
        const char* bSrcBase = B8 + (size_t)(n0 + srow) * K + scol;

#pragma unroll
        for (int i = 0; i < 8; ++i)
#pragma unroll
            for (int j = 0; j < 4; ++j)
                acc[i][j] = (int4v){0, 0, 0, 0};

        // prologue: tile0 (8 units) -> slot0; tile1 first 6 units -> slot1
        STG_A(0, 0, 0);   STG_A(0, 128, 0);
        STG_A(0, 64, 0);  STG_A(0, 192, 0);
        STG_B(0, 0, 0);   STG_B(0, 64, 0);
        STG_B(0, 128, 0); STG_B(0, 192, 0);
        STG_A(65536, 0, 128); STG_A(65536, 128, 128);
        STG_B(65536, 0, 128); STG_B(65536, 64, 128);
        STG_B(65536, 128, 128); STG_B(65536, 192, 128);
        asm volatile("s_waitcnt vmcnt(6)" ::: "memory");
        BAR();

#pragma unroll 1
        for (int it = 0; it < nit; ++it) {
            const int kO1 = (2 * it + 1) << 7;  // current odd tile, last 2 units
            const int tE = 2 * it + 2, tO = 2 * it + 3;
            const int kE = tE << 7, kO = tO << 7;
            const bool ok = tE < nkt;

            // g0: (mq0,nq0) slot0 | stage odd-tile uA2,uA3 -> slot1
            LDA(0, 0); LDB(0, 0);
            STG_A(65536, 64, kO1); STG_A(65536, 192, kO1);
            BAR(); LGKM0();
            MMA(0, 0);
            BAR();

            // g1: (mq0,nq1) slot0 | stage tE uA0,uA1 -> slot0
            LDB(1, 0);
            if (ok) { STG_A(0, 0, kE); STG_A(0, 128, kE); }
            BAR(); LGKM0();
            MMA(0, 1);
            BAR();

            // g2: (mq1,nq1) slot0 | stage tE uB0,uB1
            LDA(1, 0);
            if (ok) { STG_B(0, 0, kE); STG_B(0, 64, kE); }
            BAR(); LGKM0();
            MMA(1, 1);
            BAR();

            // g3: (mq1,nq0) slot0 | stage tE uB2,uB3 | gate slot1
            if (ok) { STG_B(0, 128, kE); STG_B(0, 192, kE); }
            BAR(); LGKM0();
            MMA(1, 0);
            if (ok) { asm volatile("s_waitcnt vmcnt(6)" ::: "memory"); }
            else    { asm volatile("s_waitcnt vmcnt(0)" ::: "memory"); }
            BAR();

            // g4: (mq0,nq0) slot1 | stage tE uA2,uA3
            LDA(0, 65536); LDB(0, 65536);
            if (ok) { STG_A(0, 64, kE); STG_A(0, 192, kE); }
            BAR(); LGKM0();
            MMA(0, 0);
            BAR();

            // g5: (mq0,nq1) slot1 | stage tO uA0,uA1 -> slot1
            LDB(1, 65536);
            if (ok) { STG_A(65536, 0, kO); STG_A(65536, 128, kO); }
            BAR(); LGKM0();
            MMA(0, 1);
            BAR();

            // g6: (mq1,nq1) slot1 | stage tO uB0,uB1
            LDA(1, 65536);
            if (ok) { STG_B(65536, 0, kO); STG_B(65536, 64, kO); }
            BAR(); LGKM0();
            MMA(1, 1);
            BAR();

            // g7: (mq1,nq0) slot1 | stage tO uB2,uB3 | gate slot0
            if (ok) { STG_B(65536, 128, kO); STG_B(65536, 192, kO); }
            BAR(); LGKM0();
            MMA(1, 0);
            if (ok) { asm volatile("s_waitcnt vmcnt(6)" ::: "memory"); }
            else    { asm volatile("s_waitcnt vmcnt(0)" ::: "memory"); }
            BAR();
        }

        // epilogue: out = (acc + bias[col]) * scale[col]; stores drain under
        // the next tile's K-loop (persistent block — no endpgm drain here)
        float scl[4]; int bsv[4];
#pragma unroll
        for (int nj = 0; nj < 4; ++nj) {
            const int col = n0 + (wc << 6) + (nj << 4) + l15;
            scl[nj] = scale[col];
            bsv[nj] = bias[col];
        }
#pragma unroll
        for (int mi = 0; mi < 8; ++mi) {
            const int rowb = m0 + (wr << 7) + (mi << 4) + (hi16 << 2);
#pragma unroll
            for (int nj = 0; nj < 4; ++nj) {
                const int col = n0 + (wc << 6) + (nj << 4) + l15;
                float* o = out + (size_t)rowb * N + col;
#pragma unroll
                for (int r = 0; r < 4; ++r)
                    o[(size_t)r * N] = (float)(acc[mi][nj][r] + bsv[nj]) * scl[nj];
            }
        }
    }
}

// ---------------------------------------------------------------------------
// Safety fallback (slow but correct) for shapes the tiled path can't handle.
__global__ __launch_bounds__(256) void naive_kernel(
    const int* __restrict__ x, const int* __restrict__ w,
    const float* __restrict__ scale, const int* __restrict__ bias,
    float* __restrict__ out, int M, int N, int K)
{
    size_t idx = (size_t)blockIdx.x * blockDim.x + threadIdx.x;
    const size_t total = (size_t)M * N;
    const size_t stride = (size_t)gridDim.x * blockDim.x;
    for (; idx < total; idx += stride) {
        const int m = (int)(idx / N), n = (int)(idx % N);
        int acc = 0;
        for (int k = 0; k < K; ++k) acc += x[(size_t)m * K + k] * w[(size_t)n * K + k];
        out[idx] = (float)(acc + bias[n]) * scale[n];
    }
}

// ---------------------------------------------------------------------------
extern "C" void kernel_launch(void* const* d_in, const int* in_sizes, int n_in,
                              void* d_out, int out_size, void* d_ws, size_t ws_size,
                              hipStream_t stream)
{
    const int*   x     = (const int*)d_in[0];
    const int*   w     = (const int*)d_in[1];
    const float* scale = (const float*)d_in[2];
    const int*   bias  = (const int*)d_in[3];
    float*       out   = (float*)d_out;

    const int N = in_sizes[2];
    const int K = in_sizes[1] / N;
    const int M = in_sizes[0] / K;

    const size_t needA = (size_t)M * K;
    const size_t needB = (size_t)N * K;

    if (ws_size < needA + needB || (M % 256) || (N % 256) || (K % 256)) {
        naive_kernel<<<8192, 256, 0, stream>>>(x, w, scale, bias, out, M, N, K);
        return;
    }

    char* x8 = (char*)d_ws;
    char* w8 = x8 + needA;

    pack_both_kernel<<<2048, 256, 0, stream>>>(x, w, (int*)x8, (int*)w8,
                                               (int)(needA >> 2), (int)(needB >> 2));

    hipFuncSetAttribute((const void*)gemm_i8_256p,
                        hipFuncAttributeMaxDynamicSharedMemorySize, 131072);

    const int mTiles = M / 256, nTiles = N / 256;
    const int nwg = mTiles * nTiles;
    const int grid = nwg < 256 ? nwg : 256;
    const int chunked = (mTiles % 8 == 0) ? 1 : 0;
    gemm_i8_256p<<<grid, 512, 131072, stream>>>(x8, w8, scale, bias, out,
                                                M, N, K, mTiles, nTiles, chunked);
}